// Round 5
// baseline (119.523 us; speedup 1.0000x reference)
//
#include <hip/hip_runtime.h>

// Chamfer distance, B=8, N=M=8192, 3-D fp32 points — register-resident MFMA.
// d2 = xx + yy - 2x.y inside mfma_f32_32x32x16_bf16 via split-precision limbs
// packed along K (13/16 slots; validated absmax 0.0 in R4):
//   A row (query q):  [(-2q)h*3, (-2q)l*3, (-2q)h*3, qqh, qql, 1, 1, 0,0,0]
//   B col (target t): [ th*3,     th*3,     tl*3,    1, 1, tth, ttl, 0,0,0]
// Each block owns 256 cols x ALL 8192 rows: B fragments (8 col-tiles) encoded
// once into registers; per 128-row strip the wave encodes 4 A-frags and does
// 8x4 MFMA. Running col-mins in 8 regs; merged once per block (shfl + small
// LDS atomic), block emits one partial sum. No global min array, no memsets.

#define BB 8
#define NN 8192
#define BLK 256
#define CCOLS 256
#define CT 8          // col-tiles per block
#define RT 4          // row-tiles per strip per wave
#define STRIPS 16     // strips per wave (16*4 waves*128 rows = 8192)

typedef __attribute__((ext_vector_type(8))) short bf16x8;
typedef __attribute__((ext_vector_type(16))) float f32x16;

__device__ __forceinline__ unsigned f2mono(float f) {
    unsigned u = __float_as_uint(f);
    return u ^ ((unsigned)((int)u >> 31) | 0x80000000u);
}
__device__ __forceinline__ float mono2f(unsigned m) {
    unsigned u = ((int)m >= 0) ? ~m : (m ^ 0x80000000u);
    return __uint_as_float(u);
}
__device__ __forceinline__ unsigned short bfh(float v) {   // fp32 -> bf16 RNE
    unsigned u = __float_as_uint(v);
    u += 0x7FFFu + ((u >> 16) & 1u);
    return (unsigned short)(u >> 16);
}
__device__ __forceinline__ float bff(unsigned short h) {
    return __uint_as_float(((unsigned)h) << 16);
}

__device__ __forceinline__ void encA(float q0, float q1, float q2, unsigned short e[16]) {
    float v0 = -2.f*q0, v1 = -2.f*q1, v2 = -2.f*q2;
    float s2 = q0*q0 + q1*q1 + q2*q2;
    unsigned short h0 = bfh(v0), h1 = bfh(v1), h2 = bfh(v2);
    unsigned short l0 = bfh(v0 - bff(h0)), l1 = bfh(v1 - bff(h1)), l2 = bfh(v2 - bff(h2));
    unsigned short sh = bfh(s2), sl = bfh(s2 - bff(sh));
    const unsigned short one = 0x3F80;
    e[0]=h0; e[1]=h1; e[2]=h2; e[3]=l0; e[4]=l1; e[5]=l2; e[6]=h0; e[7]=h1;
    e[8]=h2; e[9]=sh; e[10]=sl; e[11]=one; e[12]=one; e[13]=0; e[14]=0; e[15]=0;
}
__device__ __forceinline__ void encB(float w0, float w1, float w2, unsigned short e[16]) {
    float s2 = w0*w0 + w1*w1 + w2*w2;
    unsigned short h0 = bfh(w0), h1 = bfh(w1), h2 = bfh(w2);
    unsigned short l0 = bfh(w0 - bff(h0)), l1 = bfh(w1 - bff(h1)), l2 = bfh(w2 - bff(h2));
    unsigned short sh = bfh(s2), sl = bfh(s2 - bff(sh));
    const unsigned short one = 0x3F80;
    e[0]=h0; e[1]=h1; e[2]=h2; e[3]=h0; e[4]=h1; e[5]=h2; e[6]=l0; e[7]=l1;
    e[8]=l2; e[9]=one; e[10]=one; e[11]=sh; e[12]=sl; e[13]=0; e[14]=0; e[15]=0;
}

// grid: 512 = (dir<<8) | (b<<5) | cc ; block 256
__global__ __launch_bounds__(BLK, 2) void
main_kernel(const float* __restrict__ x, const float* __restrict__ y,
            float* __restrict__ bpart) {
    __shared__ unsigned colmin[CCOLS];
    __shared__ float red[4];
    const int bi  = blockIdx.x;
    const int dir = bi >> 8;
    const int b   = (bi >> 5) & 7;
    const int cc  = bi & 31;
    const float* A  = dir ? y : x;   // rows (minned over)
    const float* Bp = dir ? x : y;   // cols (own the mins)
    const int tid = threadIdx.x;
    const int lane = tid & 63, w = tid >> 6;
    const int m = lane & 31, h = lane >> 5;

    colmin[tid] = 0xFFFFFFFFu;       // barrier comes after the hot loop

    // encode this block's 8 B col-tile fragments into registers
    bf16x8 bf[CT];
#pragma unroll
    for (int ct = 0; ct < CT; ++ct) {
        int c = b * NN + cc * CCOLS + ct * 32 + m;
        union { unsigned short e[16]; bf16x8 v[2]; } u;
        encB(Bp[3*c], Bp[3*c+1], Bp[3*c+2], u.e);
        bf[ct] = u.v[h];
    }

    f32x16 zro;
#pragma unroll
    for (int i = 0; i < 16; ++i) zro[i] = 0.f;

    float rm[CT];
#pragma unroll
    for (int ct = 0; ct < CT; ++ct) rm[ct] = 3.4e38f;

#pragma unroll 1
    for (int s = 0; s < STRIPS; ++s) {
        bf16x8 af[RT];
#pragma unroll
        for (int t = 0; t < RT; ++t) {
            int r = b * NN + s * 512 + w * 128 + t * 32 + m;
            union { unsigned short e[16]; bf16x8 v[2]; } u;
            encA(A[3*r], A[3*r+1], A[3*r+2], u.e);
            af[t] = u.v[h];
        }
#pragma unroll
        for (int ct = 0; ct < CT; ++ct) {
            f32x16 a0 = __builtin_amdgcn_mfma_f32_32x32x16_bf16(af[0], bf[ct], zro, 0, 0, 0);
            f32x16 a1 = __builtin_amdgcn_mfma_f32_32x32x16_bf16(af[1], bf[ct], zro, 0, 0, 0);
            f32x16 a2 = __builtin_amdgcn_mfma_f32_32x32x16_bf16(af[2], bf[ct], zro, 0, 0, 0);
            f32x16 a3 = __builtin_amdgcn_mfma_f32_32x32x16_bf16(af[3], bf[ct], zro, 0, 0, 0);
            float p = rm[ct];
#pragma unroll
            for (int r = 0; r < 16; ++r) {
                float t0 = fminf(fminf(a0[r], a1[r]), a2[r]);   // v_min3
                p = fminf(fminf(t0, a3[r]), p);                 // v_min3
            }
            rm[ct] = p;
        }
    }

    // merge h-halves in-wave, then across the 4 waves via small LDS atomics
#pragma unroll
    for (int ct = 0; ct < CT; ++ct) {
        float p = fminf(rm[ct], __shfl_xor(rm[ct], 32, 64));
        if (h == 0) atomicMin(&colmin[ct * 32 + m], f2mono(p));
    }
    __syncthreads();

    // colmin[tid] is the FINAL min-d2 for col (cc*256 + tid)
    float d = sqrtf(fmaxf(mono2f(colmin[tid]), 0.f) + 1e-10f);
#pragma unroll
    for (int off = 32; off; off >>= 1) d += __shfl_down(d, off, 64);
    if (lane == 0) red[w] = d;
    __syncthreads();
    if (tid == 0) bpart[bi] = red[0] + red[1] + red[2] + red[3];
}

// 1 block, 512 threads: combine 512 partials -> final scalar
__global__ void fin_kernel(const float* __restrict__ bpart, float* __restrict__ out) {
    __shared__ float g[16];
    const int t = threadIdx.x;
    float v = bpart[t];
#pragma unroll
    for (int off = 16; off; off >>= 1) v += __shfl_down(v, off, 32);
    if ((t & 31) == 0) g[t >> 5] = v;
    __syncthreads();
    if (t == 0) {
        float acc = 0.f;
        for (int b = 0; b < BB; ++b) acc += fmaxf(g[b], g[BB + b]);
        out[0] = acc * (1.0f / (float)NN);
    }
}

extern "C" void kernel_launch(void* const* d_in, const int* in_sizes, int n_in,
                              void* d_out, int out_size, void* d_ws, size_t ws_size,
                              hipStream_t stream) {
    const float* x = (const float*)d_in[0];
    const float* y = (const float*)d_in[1];
    float* out = (float*)d_out;
    float* bpart = (float*)d_ws;     // 512 floats, written before read

    main_kernel<<<512, BLK, 0, stream>>>(x, y, bpart);
    fin_kernel<<<1, 512, 0, stream>>>(bpart, out);
}

// Round 6
// 104.101 us; speedup vs baseline: 1.1481x; 1.1481x over previous
//
#include <hip/hip_runtime.h>

// Chamfer distance, B=8, N=M=8192, 3-D fp32 points — register-resident MFMA.
// d2 = xx + yy - 2x.y inside mfma_f32_32x32x16_bf16 via split-precision limbs
// packed along K (13/16 slots; validated absmax 0.0 in R4/R5):
//   A row (query q):  [(-2q)h*3, (-2q)l*3, (-2q)h*3, qqh, qql, 1, 1, 0,0,0]
//   B col (target t): [ th*3,     th*3,     tl*3,    1, 1, tth, ttl, 0,0,0]
// R6: fragments built with pack+cndmask (NO memory unions — R5's union was
// promoted to LDS by the compiler: 16 KB extra LDS + 3.4M bank conflicts).

#define BB 8
#define NN 8192
#define BLK 256
#define CCOLS 256
#define CT 8          // col-tiles per block
#define RT 4          // row-tiles per strip per wave
#define STRIPS 16     // strips: 16 * 4 waves * 128 rows = 8192

typedef __attribute__((ext_vector_type(8))) short bf16x8;
typedef __attribute__((ext_vector_type(16))) float f32x16;
typedef __attribute__((ext_vector_type(4))) unsigned int u32x4;

__device__ __forceinline__ unsigned f2mono(float f) {
    unsigned u = __float_as_uint(f);
    return u ^ ((unsigned)((int)u >> 31) | 0x80000000u);
}
__device__ __forceinline__ float mono2f(unsigned m) {
    unsigned u = ((int)m >= 0) ? ~m : (m ^ 0x80000000u);
    return __uint_as_float(u);
}
__device__ __forceinline__ unsigned short bfh(float v) {   // fp32 -> bf16 RNE
    unsigned u = __float_as_uint(v);
    u += 0x7FFFu + ((u >> 16) & 1u);
    return (unsigned short)(u >> 16);
}
__device__ __forceinline__ float bff(unsigned short h) {
    return __uint_as_float(((unsigned)h) << 16);
}
__device__ __forceinline__ unsigned pk(unsigned lo, unsigned hi) {
    return (lo & 0xFFFFu) | (hi << 16);
}

struct Limbs { unsigned h0, h1, h2, l0, l1, l2, sh, sl; };

__device__ __forceinline__ Limbs limbs(float w0, float w1, float w2, float scale) {
    float v0 = scale * w0, v1 = scale * w1, v2 = scale * w2;
    float s2 = w0*w0 + w1*w1 + w2*w2;
    Limbs L;
    L.h0 = bfh(v0); L.h1 = bfh(v1); L.h2 = bfh(v2);
    L.l0 = bfh(v0 - bff(L.h0)); L.l1 = bfh(v1 - bff(L.h1)); L.l2 = bfh(v2 - bff(L.h2));
    L.sh = bfh(s2); L.sl = bfh(s2 - bff(L.sh));
    return L;
}

// K-half fragment selection: 4 packs per side + 4 v_cndmask. hi = (lane>>5).
__device__ __forceinline__ bf16x8 fragA(const Limbs& L, bool hi) {
    const unsigned one = 0x3F80u;
    u32x4 v;
    v[0] = hi ? pk(L.h2, L.sh) : pk(L.h0, L.h1);
    v[1] = hi ? pk(L.sl, one)  : pk(L.h2, L.l0);
    v[2] = hi ? pk(one, 0u)    : pk(L.l1, L.l2);
    v[3] = hi ? 0u             : pk(L.h0, L.h1);
    return __builtin_bit_cast(bf16x8, v);
}
__device__ __forceinline__ bf16x8 fragB(const Limbs& L, bool hi) {
    const unsigned one = 0x3F80u;
    u32x4 v;
    v[0] = hi ? pk(L.l2, one)  : pk(L.h0, L.h1);
    v[1] = hi ? pk(one, L.sh)  : pk(L.h2, L.h0);
    v[2] = hi ? pk(L.sl, 0u)   : pk(L.h1, L.h2);
    v[3] = hi ? 0u             : pk(L.l0, L.l1);
    return __builtin_bit_cast(bf16x8, v);
}

// grid: 512 = (dir<<8) | (b<<5) | cc ; block 256
__global__ __launch_bounds__(BLK, 2) void
main_kernel(const float* __restrict__ x, const float* __restrict__ y,
            float* __restrict__ bpart) {
    __shared__ unsigned colmin[CCOLS];
    __shared__ float red[4];
    const int bi  = blockIdx.x;
    const int dir = bi >> 8;
    const int b   = (bi >> 5) & 7;
    const int cc  = bi & 31;
    const float* A  = dir ? y : x;   // rows (minned over)
    const float* Bp = dir ? x : y;   // cols (own the mins)
    const int tid = threadIdx.x;
    const int lane = tid & 63, w = tid >> 6;
    const int m = lane & 31;
    const bool hb = (lane >> 5) != 0;

    colmin[tid] = 0xFFFFFFFFu;       // barrier comes after the hot loop

    // encode this block's 8 B col-tile fragments into registers
    bf16x8 bf[CT];
#pragma unroll
    for (int ct = 0; ct < CT; ++ct) {
        int c = b * NN + cc * CCOLS + ct * 32 + m;
        bf[ct] = fragB(limbs(Bp[3*c], Bp[3*c+1], Bp[3*c+2], 1.f), hb);
    }

    f32x16 zro;
#pragma unroll
    for (int i = 0; i < 16; ++i) zro[i] = 0.f;

    float rm[CT];
#pragma unroll
    for (int ct = 0; ct < CT; ++ct) rm[ct] = 3.4e38f;

#pragma unroll 1
    for (int s = 0; s < STRIPS; ++s) {
        bf16x8 af[RT];
#pragma unroll
        for (int t = 0; t < RT; ++t) {
            int r = b * NN + s * 512 + w * 128 + t * 32 + m;
            af[t] = fragA(limbs(A[3*r], A[3*r+1], A[3*r+2], -2.f), hb);
        }
#pragma unroll
        for (int ct = 0; ct < CT; ++ct) {
            f32x16 a0 = __builtin_amdgcn_mfma_f32_32x32x16_bf16(af[0], bf[ct], zro, 0, 0, 0);
            f32x16 a1 = __builtin_amdgcn_mfma_f32_32x32x16_bf16(af[1], bf[ct], zro, 0, 0, 0);
            f32x16 a2 = __builtin_amdgcn_mfma_f32_32x32x16_bf16(af[2], bf[ct], zro, 0, 0, 0);
            f32x16 a3 = __builtin_amdgcn_mfma_f32_32x32x16_bf16(af[3], bf[ct], zro, 0, 0, 0);
            float p = rm[ct];
#pragma unroll
            for (int r = 0; r < 16; ++r) {
                float t0 = fminf(fminf(a0[r], a1[r]), a2[r]);   // v_min3
                p = fminf(fminf(t0, a3[r]), p);                 // v_min3
            }
            rm[ct] = p;
        }
    }

    // merge K-halves in-wave, then across the 4 waves via small LDS atomics
#pragma unroll
    for (int ct = 0; ct < CT; ++ct) {
        float p = fminf(rm[ct], __shfl_xor(rm[ct], 32, 64));
        if (!hb) atomicMin(&colmin[ct * 32 + m], f2mono(p));
    }
    __syncthreads();

    // colmin[tid] is the FINAL min-d2 for col (cc*256 + tid)
    float d = sqrtf(fmaxf(mono2f(colmin[tid]), 0.f) + 1e-10f);
#pragma unroll
    for (int off = 32; off; off >>= 1) d += __shfl_down(d, off, 64);
    if (lane == 0) red[w] = d;
    __syncthreads();
    if (tid == 0) bpart[bi] = red[0] + red[1] + red[2] + red[3];
}

// 1 block, 512 threads: combine 512 partials -> final scalar
__global__ void fin_kernel(const float* __restrict__ bpart, float* __restrict__ out) {
    __shared__ float g[16];
    const int t = threadIdx.x;
    float v = bpart[t];
#pragma unroll
    for (int off = 16; off; off >>= 1) v += __shfl_down(v, off, 32);
    if ((t & 31) == 0) g[t >> 5] = v;
    __syncthreads();
    if (t == 0) {
        float acc = 0.f;
        for (int b = 0; b < BB; ++b) acc += fmaxf(g[b], g[BB + b]);
        out[0] = acc * (1.0f / (float)NN);
    }
}

extern "C" void kernel_launch(void* const* d_in, const int* in_sizes, int n_in,
                              void* d_out, int out_size, void* d_ws, size_t ws_size,
                              hipStream_t stream) {
    const float* x = (const float*)d_in[0];
    const float* y = (const float*)d_in[1];
    float* out = (float*)d_out;
    float* bpart = (float*)d_ws;     // 512 floats, written before read

    main_kernel<<<512, BLK, 0, stream>>>(x, y, bpart);
    fin_kernel<<<1, 512, 0, stream>>>(bpart, out);
}

// Round 7
// 101.979 us; speedup vs baseline: 1.1720x; 1.0208x over previous
//
#include <hip/hip_runtime.h>

// Chamfer distance, B=8, N=M=8192, 3-D fp32 points — pre-encoded MFMA frags.
// d2 = xx + yy - 2x.y inside mfma_f32_32x32x16_bf16 via split-precision limbs
// packed along K (13/16 slots; absmax 0.0 in R4-R6):
//   A row (query q):  [(-2q)h*3, (-2q)l*3, (-2q)h*3, qqh, qql, 1, 1, 0,0,0]
//   B col (target t): [ th*3,     th*3,     tl*3,    1, 1, tth, ttl, 0,0,0]
// R7: prep kernel encodes each point's A-frag + B-frag ONCE (R6 re-encoded
// every A row 32x in-loop = dominant VALU). Hot loop: dwordx4 frag loads
// (coalesced), software prefetch, 8 v_min3 per MFMA (floor). Fin fused via
// last-block counter. 2 dispatches, no memsets.

#define BB 8
#define NN 8192
#define NPTS (BB*NN)  // 65536
#define BLK 256
#define CCOLS 256
#define CT 8          // col-tiles per block
#define RT 4          // row-tiles per strip per wave
#define STRIPS 16     // 16 strips * 4 waves * 128 rows = 8192

typedef __attribute__((ext_vector_type(8))) short bf16x8;
typedef __attribute__((ext_vector_type(16))) float f32x16;

__device__ __forceinline__ unsigned f2mono(float f) {
    unsigned u = __float_as_uint(f);
    return u ^ ((unsigned)((int)u >> 31) | 0x80000000u);
}
__device__ __forceinline__ float mono2f(unsigned m) {
    unsigned u = ((int)m >= 0) ? ~m : (m ^ 0x80000000u);
    return __uint_as_float(u);
}
__device__ __forceinline__ unsigned bfh(float v) {   // fp32 -> bf16 RNE
    unsigned u = __float_as_uint(v);
    u += 0x7FFFu + ((u >> 16) & 1u);
    return u >> 16;
}
__device__ __forceinline__ float bff(unsigned h) {
    return __uint_as_float(h << 16);
}
__device__ __forceinline__ unsigned pk(unsigned lo, unsigned hi) {
    return (lo & 0xFFFFu) | (hi << 16);
}

// grid 512, block 256: one thread per point (x: [0,NPTS), y: [NPTS,2*NPTS))
__global__ void prep_kernel(const float* __restrict__ x, const float* __restrict__ y,
                            uint4* __restrict__ afr, uint4* __restrict__ bfr,
                            unsigned* __restrict__ counter) {
    int i = blockIdx.x * BLK + threadIdx.x;
    if (i == 0) *counter = 0;
    const float* src = (i < NPTS) ? x : y;
    int j = (i < NPTS) ? i : i - NPTS;
    float c0 = src[3*j], c1 = src[3*j+1], c2 = src[3*j+2];
    float s2 = c0*c0 + c1*c1 + c2*c2;
    unsigned sh = bfh(s2), sl = bfh(s2 - bff(sh));
    float a0 = -2.f*c0, a1 = -2.f*c1, a2 = -2.f*c2;
    unsigned ah0 = bfh(a0), ah1 = bfh(a1), ah2 = bfh(a2);
    unsigned al0 = bfh(a0 - bff(ah0)), al1 = bfh(a1 - bff(ah1)), al2 = bfh(a2 - bff(ah2));
    unsigned bh0 = bfh(c0), bh1 = bfh(c1), bh2 = bfh(c2);
    unsigned bl0 = bfh(c0 - bff(bh0)), bl1 = bfh(c1 - bff(bh1)), bl2 = bfh(c2 - bff(bh2));
    const unsigned one = 0x3F80u;
    afr[2*i]   = make_uint4(pk(ah0,ah1), pk(ah2,al0), pk(al1,al2), pk(ah0,ah1));
    afr[2*i+1] = make_uint4(pk(ah2,sh),  pk(sl,one),  pk(one,0u),  0u);
    bfr[2*i]   = make_uint4(pk(bh0,bh1), pk(bh2,bh0), pk(bh1,bh2), pk(bl0,bl1));
    bfr[2*i+1] = make_uint4(pk(bl2,one), pk(one,sh),  pk(sl,0u),   0u);
}

__device__ __forceinline__ bf16x8 cvt(uint4 v) { return __builtin_bit_cast(bf16x8, v); }

// grid: 512 = (dir<<8) | (b<<5) | cc ; block 256
__global__ __launch_bounds__(BLK, 2) void
main_kernel(const uint4* __restrict__ afr, const uint4* __restrict__ bfr,
            float* __restrict__ bpart, unsigned* __restrict__ counter,
            float* __restrict__ out) {
    __shared__ unsigned colmin[CCOLS];
    __shared__ float red[4];
    __shared__ float gg[8];
    __shared__ int lastflag;
    const int bi  = blockIdx.x;
    const int dir = bi >> 8;
    const int b   = (bi >> 5) & 7;
    const int cc  = bi & 31;
    const uint4* Af = afr + (dir ? 2*NPTS : 0);        // A rows: dir? y : x
    const uint4* Bf = bfr + (dir ? 0 : 2*NPTS);        // B cols: dir? x : y
    const int tid = threadIdx.x;
    const int lane = tid & 63, w = tid >> 6;
    const int m = lane & 31;
    const int hb = lane >> 5;

    colmin[tid] = 0xFFFFFFFFu;       // barrier comes after the hot loop

    // this block's 8 B col-tile fragments -> registers (coalesced dwordx4)
    bf16x8 bf[CT];
#pragma unroll
    for (int ct = 0; ct < CT; ++ct) {
        int c = b * NN + cc * CCOLS + ct * 32 + m;
        bf[ct] = cvt(Bf[2*c + hb]);
    }

    f32x16 zro;
#pragma unroll
    for (int i = 0; i < 16; ++i) zro[i] = 0.f;

    float rm[CT];
#pragma unroll
    for (int ct = 0; ct < CT; ++ct) rm[ct] = 3.4e38f;

    const int rowbase = b * NN + w * 128 + m;
    uint4 cur[RT], nxt[RT];
#pragma unroll
    for (int t = 0; t < RT; ++t) cur[t] = Af[2*(rowbase + t*32) + hb];

#pragma unroll 1
    for (int s = 0; s < STRIPS; ++s) {
        const int np = (s + 1 < STRIPS) ? (s + 1) : s;   // prefetch next strip
#pragma unroll
        for (int t = 0; t < RT; ++t) nxt[t] = Af[2*(rowbase + np*512 + t*32) + hb];
#pragma unroll
        for (int ct = 0; ct < CT; ++ct) {
            f32x16 a0 = __builtin_amdgcn_mfma_f32_32x32x16_bf16(cvt(cur[0]), bf[ct], zro, 0, 0, 0);
            f32x16 a1 = __builtin_amdgcn_mfma_f32_32x32x16_bf16(cvt(cur[1]), bf[ct], zro, 0, 0, 0);
            f32x16 a2 = __builtin_amdgcn_mfma_f32_32x32x16_bf16(cvt(cur[2]), bf[ct], zro, 0, 0, 0);
            f32x16 a3 = __builtin_amdgcn_mfma_f32_32x32x16_bf16(cvt(cur[3]), bf[ct], zro, 0, 0, 0);
            float p = rm[ct];
#pragma unroll
            for (int r = 0; r < 16; ++r) {
                float t0 = fminf(fminf(a0[r], a1[r]), a2[r]);   // v_min3
                p = fminf(fminf(t0, a3[r]), p);                 // v_min3
            }
            rm[ct] = p;
        }
#pragma unroll
        for (int t = 0; t < RT; ++t) cur[t] = nxt[t];
    }

    // merge K-halves in-wave, then across the 4 waves via small LDS atomics
#pragma unroll
    for (int ct = 0; ct < CT; ++ct) {
        float p = fminf(rm[ct], __shfl_xor(rm[ct], 32, 64));
        if (hb == 0) atomicMin(&colmin[ct * 32 + m], f2mono(p));
    }
    __syncthreads();

    // colmin[tid] is the FINAL min-d2 for col (cc*256 + tid)
    float d = sqrtf(fmaxf(mono2f(colmin[tid]), 0.f) + 1e-10f);
#pragma unroll
    for (int off = 32; off; off >>= 1) d += __shfl_down(d, off, 64);
    if (lane == 0) red[w] = d;
    __syncthreads();
    if (tid == 0) {
        float total = red[0] + red[1] + red[2] + red[3];
        atomicExch(&bpart[bi], total);        // device-scope coherent store
        __threadfence();
        unsigned old = atomicAdd(counter, 1u);
        lastflag = (old == 511u);
    }
    __syncthreads();

    if (lastflag) {                           // block-uniform
        float v0 = atomicAdd(&bpart[tid], 0.f);        // dir=0, group=tid>>5
        float v1 = atomicAdd(&bpart[256 + tid], 0.f);  // dir=1
#pragma unroll
        for (int off = 16; off; off >>= 1) {
            v0 += __shfl_down(v0, off, 32);
            v1 += __shfl_down(v1, off, 32);
        }
        if ((tid & 31) == 0) gg[tid >> 5] = fmaxf(v0, v1);
        __syncthreads();
        if (tid == 0) {
            float acc = 0.f;
#pragma unroll
            for (int k = 0; k < 8; ++k) acc += gg[k];
            out[0] = acc * (1.0f / (float)NN);
        }
    }
}

extern "C" void kernel_launch(void* const* d_in, const int* in_sizes, int n_in,
                              void* d_out, int out_size, void* d_ws, size_t ws_size,
                              hipStream_t stream) {
    const float* x = (const float*)d_in[0];
    const float* y = (const float*)d_in[1];
    float* out = (float*)d_out;

    char* ws = (char*)d_ws;
    uint4* afr = (uint4*)ws;                     // 2*NPTS*2 uint4 = 4 MB
    uint4* bfr = afr + 4 * NPTS;                 // 4 MB
    float* bpart = (float*)(bfr + 4 * NPTS);     // 512 floats
    unsigned* counter = (unsigned*)(bpart + 512);

    prep_kernel<<<(2 * NPTS) / BLK, BLK, 0, stream>>>(x, y, afr, bfr, counter);
    main_kernel<<<512, BLK, 0, stream>>>(afr, bfr, bpart, counter, out);
}